// Round 9
// baseline (261.751 us; speedup 1.0000x reference)
//
#include <hip/hip_runtime.h>
#include <stdint.h>

typedef __attribute__((ext_vector_type(8))) _Float16 half8;  // MFMA f16 A/B frag (4 VGPRs)
typedef __attribute__((ext_vector_type(4))) float f32x4;     // MFMA C/D frag

// B=4, C=384, Q=384, H=256, K=256
// ws: [0, 393216) Wsplit fp16 [3][256][256] = W_h, W_u, W_hu, layout [k][h]
// NOTE: w1 is (K=256 rows, 3H=768 cols): W_m[k][h] = w1[k][m*256 + h]  (axis-0 is k!)

__device__ __forceinline__ float leaky(float x) { return fmaxf(x, 0.01f * x); }

template <int CTRL>
__device__ __forceinline__ float dpp_add(float x) {
  int t = __builtin_amdgcn_update_dpp(0, __float_as_int(x), CTRL, 0xF, 0xF, true);
  return x + __int_as_float(t);
}

// 16-lane sum (within each aligned 16-lane group): xor1, xor2, then +ror4 +ror8
__device__ __forceinline__ float row16_sum(float p) {
  p = dpp_add<0xB1>(p);   // quad_perm(1,0,3,2)  = xor 1
  p = dpp_add<0x4E>(p);   // quad_perm(2,3,0,1)  = xor 2
  p = dpp_add<0x124>(p);  // row_ror:4
  p = dpp_add<0x128>(p);  // row_ror:8  -> full 16-lane sum in every lane
  return p;
}

// ---------------- K0: split w1 (256 k-rows, 768 h-cols) -> fp16 [3][k][h] -----------
__global__ void k_convert(const float* __restrict__ w1, unsigned int* __restrict__ ws) {
  int d = blockIdx.x * 256 + threadIdx.x;        // 98304 dwords (2 fp16 each, along h)
  int m = d >> 15;                               // matrix 0..2
  int rem = d & 32767;
  int k = rem >> 7;
  int h2 = (rem & 127) * 2;
  float x0 = w1[k * 768 + m * 256 + h2];         // w1[k][m*256+h] — axis-0 is k
  float x1 = w1[k * 768 + m * 256 + h2 + 1];
  unsigned short p0 = __builtin_bit_cast(unsigned short, (_Float16)x0);
  unsigned short p1 = __builtin_bit_cast(unsigned short, (_Float16)x1);
  ws[d] = (unsigned int)p0 | ((unsigned int)p1 << 16);
}

// ---------------- K1: fused main kernel ---------------------------------------------
// Block: 16 q-rows x 256 k x 24 c. 256 threads = 4 waves, wave w owns k in [w*64, w*64+64),
// lane (quad,r) holds k = w*64 + 4r + j (j = 0..3) — the VERIFIED round-3 kernel.
// Round-9 delta (ONLY two changes, zero register delta):
//  (1) per-wave c-STAGGER: wave starts its barrier-free c-loop at ((w+blk)&3)*6 and wraps
//      mod 24. The 2 resident waves/SIMD previously ran [init->MFMA->epilogue] in lockstep
//      (MfmaUtil 26 / VALUBusy 34 at 141us = phases colliding); offsetting them ~1/4 period
//      lets one wave's epilogue VALU fill the other's MFMA burst. Pure index permutation.
//  (2) s_setprio(1) around the MFMA burst (correct in R4; useful now that waves diverge).
// NOTE: waves-per-EU hint must stay 1 — every kernel built with hint>=3 failed correctness
// (R5-R8, absmax ~0.3) incl. one reusing this exact mapping; hint in {1,2} always passed.
// 2 waves/SIMD is also the structural ceiling: whu(128)+ufr(32)=160 persistent regs.
__global__ void __launch_bounds__(256, 1) k_main(
    const float* __restrict__ hp, const float* __restrict__ up,
    const _Float16* __restrict__ wsp,
    const float* __restrict__ b1, const float* __restrict__ w2,
    const float* __restrict__ b2, float* __restrict__ out) {
  __shared__ __align__(16) float thlds[24 * 256];      // term_h (pure), fp32, 24 KB
  __shared__ __align__(16) _Float16 hlds[24 * 256];    // h rows, fp16, 12 KB
  __shared__ float redw[24][4][16];                    // per-c per-wave partials, 6 KB

  const int tid = threadIdx.x;
  const int blk = blockIdx.x;            // 1536 = 4 b * 24 qt * 16 cc
  const int b = blk / 384;
  const int r0 = blk % 384;
  const int qt = r0 % 24;
  const int cc = r0 / 24;
  const int q0 = qt * 16;
  const int c0 = cc * 24;

  const int w = tid >> 6, l = tid & 63, quad = l >> 4, r = l & 15;
  const int kbase = w * 64 + r * 4;      // lane's 4 k-columns = kbase + j

  const _Float16* Wh = wsp;
  const _Float16* Wu = wsp + 65536;
  const _Float16* Whu = wsp + 131072;

  // ---- stage h rows into LDS as packed fp16, layout [c][h] linear ----
  for (int d = tid; d < 24 * 128; d += 256) {          // 3072 dwords
    int c = d >> 7;
    int hidx = (d & 127) * 2;
    const float* hr = hp + (b * 384 + c0 + c) * 256 + hidx;
    unsigned short p0 = __builtin_bit_cast(unsigned short, (_Float16)hr[0]);
    unsigned short p1 = __builtin_bit_cast(unsigned short, (_Float16)hr[1]);
    ((unsigned int*)hlds)[d] = (unsigned int)p0 | ((unsigned int)p1 << 16);
  }

  // ---- one-time register frags: u rows (A operand) ----
  half8 ufr[8];                          // u[q0+r][s*32+quad*8 .. +8]
  {
    const float* urow = up + (b * 384 + q0 + r) * 256 + quad * 8;
#pragma unroll
    for (int s = 0; s < 8; ++s) {
      float4 a0 = *(const float4*)(urow + s * 32);
      float4 a1 = *(const float4*)(urow + s * 32 + 4);
      half8 hv;
      hv[0] = (_Float16)a0.x; hv[1] = (_Float16)a0.y;
      hv[2] = (_Float16)a0.z; hv[3] = (_Float16)a0.w;
      hv[4] = (_Float16)a1.x; hv[5] = (_Float16)a1.y;
      hv[6] = (_Float16)a1.z; hv[7] = (_Float16)a1.w;
      ufr[s] = hv;
    }
  }

  // ---- tu pass: tuacc[j][ii] = b1[kbase+j] + term_u[q0+quad*4+ii][kbase+j] ----
  // (c-independent; Wu frags are transient)
  f32x4 tuacc[4];
  {
    f32x4 b1v = *(const f32x4*)(b1 + kbase);
#pragma unroll
    for (int j = 0; j < 4; ++j) tuacc[j] = (f32x4){b1v[j], b1v[j], b1v[j], b1v[j]};
#pragma unroll
    for (int s = 0; s < 8; ++s) {
#pragma unroll
      for (int j = 0; j < 4; ++j) {
        half8 wuf = *(const half8*)(Wu + (kbase + j) * 256 + s * 32 + quad * 8);
        tuacc[j] = __builtin_amdgcn_mfma_f32_16x16x32_f16(ufr[s], wuf, tuacc[j], 0, 0, 0);
      }
    }
  }

  __syncthreads();   // hlds ready

  // ---- prologue MFMA pass: term_h for the block's 24 c-rows -> thlds (pure, no b1) ----
#pragma unroll
  for (int ct = 0; ct < 2; ++ct) {
    f32x4 accq[4];
#pragma unroll
    for (int j = 0; j < 4; ++j) accq[j] = (f32x4){0.f, 0.f, 0.f, 0.f};
#pragma unroll
    for (int s = 0; s < 8; ++s) {
      half8 ha = (half8){};
      if (ct * 16 + r < 24) ha = *(const half8*)&hlds[(ct * 16 + r) * 256 + s * 32 + quad * 8];
#pragma unroll
      for (int j = 0; j < 4; ++j) {
        half8 wb = *(const half8*)(Wh + (kbase + j) * 256 + s * 32 + quad * 8);
        accq[j] = __builtin_amdgcn_mfma_f32_16x16x32_f16(ha, wb, accq[j], 0, 0, 0);
      }
    }
#pragma unroll
    for (int ii = 0; ii < 4; ++ii) {
      int crow = ct * 16 + quad * 4 + ii;
      if (crow < 24) {
        f32x4 v = {accq[0][ii], accq[1][ii], accq[2][ii], accq[3][ii]};
        *(f32x4*)&thlds[crow * 256 + kbase] = v;
      }
    }
  }

  // ---- persistent B operands: W_hu rows for this wave's 64 k (loaded late, after
  //      the prologue, so peak register pressure stays low until the c-loop) ----
  half8 whu[4][8];
#pragma unroll
  for (int j = 0; j < 4; ++j) {
    const _Float16* rowu = Whu + (kbase + j) * 256 + quad * 8;
#pragma unroll
    for (int s = 0; s < 8; ++s) whu[j][s] = *(const half8*)(rowu + s * 32);
  }

  __syncthreads();   // thlds ready

  // ---- main c-loop: barrier-free, per-wave STAGGERED start ----
  f32x4 w2v = *(const f32x4*)(w2 + kbase);
  f32x4 w2a = w2v * 0.505f;     // leaky(x)*w2 = w2*(0.505x + 0.495|x|)
  f32x4 w2b = w2v * 0.495f;

  const int coff = ((w + blk) & 3) * 6;   // 0,6,12,18 — decorrelates co-resident waves

#pragma unroll 1
  for (int t = 0; t < 24; ++t) {
    int c = t + coff;
    if (c >= 24) c -= 24;

    f32x4 thv = *(const f32x4*)&thlds[c * 256 + kbase];
    f32x4 acc[4];
#pragma unroll
    for (int j = 0; j < 4; ++j) {
      float tt = thv[j];
      acc[j] = tuacc[j] + (f32x4){tt, tt, tt, tt};
    }

    __builtin_amdgcn_s_setprio(1);
#pragma unroll
    for (int s = 0; s < 8; ++s) {
      half8 hc = *(const half8*)&hlds[c * 256 + s * 32 + quad * 8];
      half8 au = ufr[s] * hc;                         // v_pk_mul_f16: A = u ⊙ h[c]
#pragma unroll
      for (int j = 0; j < 4; ++j)
        acc[j] = __builtin_amdgcn_mfma_f32_16x16x32_f16(au, whu[j][s], acc[j], 0, 0, 0);
    }
    __builtin_amdgcn_s_setprio(0);

    // epilogue: layer-2 dot over this wave's 64 k, DPP-reduce over the 16 r-lanes
#pragma unroll
    for (int ii = 0; ii < 4; ++ii) {
      float p = 0.f;
#pragma unroll
      for (int j = 0; j < 4; ++j) {
        float sv = acc[j][ii];
        p = fmaf(w2a[j], sv, p);
        p = fmaf(w2b[j], fabsf(sv), p);
      }
      p = row16_sum(p);
      if (r == 0) redw[c][w][quad * 4 + ii] = p;
    }
  }

  __syncthreads();   // all partials in redw

  // ---- final cross-wave combine + bias + leaky + store ----
  const float b2v = b2[0];
  for (int idx = tid; idx < 24 * 16; idx += 256) {
    int c = idx >> 4;
    int q = idx & 15;
    float o = redw[c][0][q] + redw[c][1][q] + redw[c][2][q] + redw[c][3][q] + b2v;
    out[(b * 384 + c0 + c) * 384 + q0 + q] = leaky(o);
  }
}

extern "C" void kernel_launch(void* const* d_in, const int* in_sizes, int n_in,
                              void* d_out, int out_size, void* d_ws, size_t ws_size,
                              hipStream_t stream) {
  const float* hp = (const float*)d_in[0];   // (4,384,256)
  const float* up = (const float*)d_in[1];   // (4,384,256)
  const float* w1 = (const float*)d_in[2];   // (256,768) — axis-0 is k
  const float* b1 = (const float*)d_in[3];   // (256,)
  const float* w2 = (const float*)d_in[4];   // (1,256)
  const float* b2 = (const float*)d_in[5];   // (1,)
  float* out = (float*)d_out;                // (4,384,384)

  unsigned int* wsplit = (unsigned int*)d_ws;   // fp16 [3][256][256]

  k_convert<<<384, 256, 0, stream>>>(w1, wsplit);
  k_main<<<1536, 256, 0, stream>>>(hp, up, (const _Float16*)d_ws, b1, w2, b2, out);
}

// Round 10
// 214.970 us; speedup vs baseline: 1.2176x; 1.2176x over previous
//
#include <hip/hip_runtime.h>
#include <stdint.h>

typedef __attribute__((ext_vector_type(8))) _Float16 half8;  // MFMA f16 A/B frag (4 VGPRs)
typedef __attribute__((ext_vector_type(4))) float f32x4;     // MFMA C/D frag

// B=4, C=384, Q=384, H=256, K=256
// ws: [0, 393216) Wsplit fp16 [3][256][256] = W_h, W_u, W_hu, layout [k][h]
// NOTE: w1 is (K=256 rows, 3H=768 cols): W_m[k][h] = w1[k][m*256 + h]  (axis-0 is k!)

__device__ __forceinline__ float leaky(float x) { return fmaxf(x, 0.01f * x); }

template <int CTRL>
__device__ __forceinline__ float dpp_add(float x) {
  int t = __builtin_amdgcn_update_dpp(0, __float_as_int(x), CTRL, 0xF, 0xF, true);
  return x + __int_as_float(t);
}

// 16-lane sum (within each aligned 16-lane group): xor1, xor2, then +ror4 +ror8
__device__ __forceinline__ float row16_sum(float p) {
  p = dpp_add<0xB1>(p);   // quad_perm(1,0,3,2)  = xor 1
  p = dpp_add<0x4E>(p);   // quad_perm(2,3,0,1)  = xor 2
  p = dpp_add<0x124>(p);  // row_ror:4
  p = dpp_add<0x128>(p);  // row_ror:8  -> full 16-lane sum in every lane
  return p;
}

// ---------------- K0: split w1 (256 k-rows, 768 h-cols) -> fp16 [3][k][h] -----------
__global__ void k_convert(const float* __restrict__ w1, unsigned int* __restrict__ ws) {
  int d = blockIdx.x * 256 + threadIdx.x;        // 98304 dwords (2 fp16 each, along h)
  int m = d >> 15;                               // matrix 0..2
  int rem = d & 32767;
  int k = rem >> 7;
  int h2 = (rem & 127) * 2;
  float x0 = w1[k * 768 + m * 256 + h2];         // w1[k][m*256+h] — axis-0 is k
  float x1 = w1[k * 768 + m * 256 + h2 + 1];
  unsigned short p0 = __builtin_bit_cast(unsigned short, (_Float16)x0);
  unsigned short p1 = __builtin_bit_cast(unsigned short, (_Float16)x1);
  ws[d] = (unsigned int)p0 | ((unsigned int)p1 << 16);
}

// ---------------- K1: fused main kernel ---------------------------------------------
// Block: 16 q-rows x 256 k x 24 c. 256 threads = 4 waves, wave w owns k in [w*64, w*64+64),
// lane (quad,r) holds k = w*64 + 4r + j (j = 0..3) — the VERIFIED round-3 mapping.
// Round-10: j-split two-pass (R8 structure) at hint=2.
//   Evidence table: hint{1,2} -> 5/5 correct (incl. R2 which spilled heavily);
//   hint{3,4} -> 0/4 correct (R5-R8, three different algebras, absmax~0.3).
//   R8's j-split algebra was byte-identical to R3 except the split + hint=3 ->
//   the split is presumed sound; the hint>=3 compile mode is retired.
// Point of the split: resident W_hu drops 128->64 regs. Live ~155-165 total (all VGPR,
//   no AGPR residue). If allocator lands <=170 -> 3 waves/SIMD (vs R3's 2, which sat at
//   exactly 256 regs: any +1 VGPR halves it, proven by R4/R9).
// tuacc[4] computed ONCE (not per pass): +8 regs, -16 MFMAs vs R8.
// sched_barrier+syncthreads between passes: allocator must not overlap wA/wB lifetimes.
__global__ void __launch_bounds__(256, 2) k_main(
    const float* __restrict__ hp, const float* __restrict__ up,
    const _Float16* __restrict__ wsp,
    const float* __restrict__ b1, const float* __restrict__ w2,
    const float* __restrict__ b2, float* __restrict__ out) {
  __shared__ __align__(16) float thlds[24 * 256];      // term_h (pure), fp32, 24 KB
  __shared__ __align__(16) _Float16 hlds[24 * 256];    // h rows, fp16, 12 KB
  __shared__ float redw[24][4][16];                    // per-c per-wave partials, 6 KB

  const int tid = threadIdx.x;
  const int blk = blockIdx.x;            // 1536 = 4 b * 24 qt * 16 cc
  const int b = blk / 384;
  const int r0 = blk % 384;
  const int qt = r0 % 24;
  const int cc = r0 / 24;
  const int q0 = qt * 16;
  const int c0 = cc * 24;

  const int w = tid >> 6, l = tid & 63, quad = l >> 4, r = l & 15;
  const int kbase = w * 64 + r * 4;      // lane's 4 k-columns = kbase + j

  const _Float16* Wh = wsp;
  const _Float16* Wu = wsp + 65536;
  const _Float16* Whu = wsp + 131072;

  // ---- stage h rows into LDS as packed fp16, layout [c][h] linear ----
  for (int d = tid; d < 24 * 128; d += 256) {          // 3072 dwords
    int c = d >> 7;
    int hidx = (d & 127) * 2;
    const float* hr = hp + (b * 384 + c0 + c) * 256 + hidx;
    unsigned short p0 = __builtin_bit_cast(unsigned short, (_Float16)hr[0]);
    unsigned short p1 = __builtin_bit_cast(unsigned short, (_Float16)hr[1]);
    ((unsigned int*)hlds)[d] = (unsigned int)p0 | ((unsigned int)p1 << 16);
  }

  // ---- one-time register frags: u rows (A operand) ----
  half8 ufr[8];                          // u[q0+r][s*32+quad*8 .. +8]
  {
    const float* urow = up + (b * 384 + q0 + r) * 256 + quad * 8;
#pragma unroll
    for (int s = 0; s < 8; ++s) {
      float4 a0 = *(const float4*)(urow + s * 32);
      float4 a1 = *(const float4*)(urow + s * 32 + 4);
      half8 hv;
      hv[0] = (_Float16)a0.x; hv[1] = (_Float16)a0.y;
      hv[2] = (_Float16)a0.z; hv[3] = (_Float16)a0.w;
      hv[4] = (_Float16)a1.x; hv[5] = (_Float16)a1.y;
      hv[6] = (_Float16)a1.z; hv[7] = (_Float16)a1.w;
      ufr[s] = hv;
    }
  }

  // ---- tu pass (once): tuacc[j][ii] = b1[kbase+j] + term_u[q0+quad*4+ii][kbase+j] ----
  f32x4 tuacc[4];
  {
    f32x4 b1v = *(const f32x4*)(b1 + kbase);
#pragma unroll
    for (int j = 0; j < 4; ++j) tuacc[j] = (f32x4){b1v[j], b1v[j], b1v[j], b1v[j]};
#pragma unroll
    for (int s = 0; s < 8; ++s) {
#pragma unroll
      for (int j = 0; j < 4; ++j) {
        half8 wuf = *(const half8*)(Wu + (kbase + j) * 256 + s * 32 + quad * 8);
        tuacc[j] = __builtin_amdgcn_mfma_f32_16x16x32_f16(ufr[s], wuf, tuacc[j], 0, 0, 0);
      }
    }
  }

  __syncthreads();   // hlds ready

  // ---- prologue MFMA pass: term_h for the block's 24 c-rows -> thlds (pure, no b1) ----
#pragma unroll
  for (int ct = 0; ct < 2; ++ct) {
    f32x4 accq[4];
#pragma unroll
    for (int j = 0; j < 4; ++j) accq[j] = (f32x4){0.f, 0.f, 0.f, 0.f};
#pragma unroll
    for (int s = 0; s < 8; ++s) {
      half8 ha = (half8){};
      if (ct * 16 + r < 24) ha = *(const half8*)&hlds[(ct * 16 + r) * 256 + s * 32 + quad * 8];
#pragma unroll
      for (int j = 0; j < 4; ++j) {
        half8 wb = *(const half8*)(Wh + (kbase + j) * 256 + s * 32 + quad * 8);
        accq[j] = __builtin_amdgcn_mfma_f32_16x16x32_f16(ha, wb, accq[j], 0, 0, 0);
      }
    }
#pragma unroll
    for (int ii = 0; ii < 4; ++ii) {
      int crow = ct * 16 + quad * 4 + ii;
      if (crow < 24) {
        f32x4 v = {accq[0][ii], accq[1][ii], accq[2][ii], accq[3][ii]};
        *(f32x4*)&thlds[crow * 256 + kbase] = v;
      }
    }
  }
  __syncthreads();   // thlds ready

  // ---- one pass: j in {2p, 2p+1}; literal pass index -> all j-indices constant-fold ----
  auto do_pass = [&](const int p) __attribute__((always_inline)) {
    const int j0 = 2 * p, j1 = 2 * p + 1;

    // resident B operands for this pass: W_hu rows kbase+j0, kbase+j1 (64 VGPRs)
    half8 wA[8], wB[8];
#pragma unroll
    for (int s = 0; s < 8; ++s) {
      wA[s] = *(const half8*)(Whu + (kbase + j0) * 256 + s * 32 + quad * 8);
      wB[s] = *(const half8*)(Whu + (kbase + j1) * 256 + s * 32 + quad * 8);
    }

    const float w2_0 = w2[kbase + j0];
    const float w2_1 = w2[kbase + j1];
    const float w2a0 = w2_0 * 0.505f, w2b0 = w2_0 * 0.495f;   // leaky(x)*w2
    const float w2a1 = w2_1 * 0.505f, w2b1 = w2_1 * 0.495f;

#pragma unroll 1
    for (int c = 0; c < 24; ++c) {
      float2 thv = *(const float2*)&thlds[c * 256 + kbase + j0];   // j0 even -> 8B aligned
      f32x4 acc0 = tuacc[j0] + (f32x4){thv.x, thv.x, thv.x, thv.x};
      f32x4 acc1 = tuacc[j1] + (f32x4){thv.y, thv.y, thv.y, thv.y};

      __builtin_amdgcn_s_setprio(1);
#pragma unroll
      for (int s = 0; s < 8; ++s) {
        half8 hc = *(const half8*)&hlds[c * 256 + s * 32 + quad * 8];
        half8 au = ufr[s] * hc;                       // v_pk_mul_f16: A = u ⊙ h[c]
        acc0 = __builtin_amdgcn_mfma_f32_16x16x32_f16(au, wA[s], acc0, 0, 0, 0);
        acc1 = __builtin_amdgcn_mfma_f32_16x16x32_f16(au, wB[s], acc1, 0, 0, 0);
      }
      __builtin_amdgcn_s_setprio(0);

      // epilogue: layer-2 dot over this pass's 32 k, DPP-reduce over the 16 r-lanes
#pragma unroll
      for (int ii = 0; ii < 4; ++ii) {
        float s0 = acc0[ii], s1 = acc1[ii];
        float pv = 0.f;
        pv = fmaf(w2a0, s0, pv);
        pv = fmaf(w2b0, fabsf(s0), pv);
        pv = fmaf(w2a1, s1, pv);
        pv = fmaf(w2b1, fabsf(s1), pv);
        pv = row16_sum(pv);
        if (r == 0) {
          if (p == 0) redw[c][w][quad * 4 + ii] = pv;      // literal p: folds
          else        redw[c][w][quad * 4 + ii] += pv;     // same-lane RMW, ordered
        }
      }
    }
  };

  do_pass(0);
  __builtin_amdgcn_sched_barrier(0);   // do not overlap pass lifetimes (reg pressure)
  __syncthreads();
  __builtin_amdgcn_sched_barrier(0);
  do_pass(1);

  __syncthreads();   // all partials in redw

  // ---- final cross-wave combine + bias + leaky + store ----
  const float b2v = b2[0];
  for (int idx = tid; idx < 24 * 16; idx += 256) {
    int c = idx >> 4;
    int q = idx & 15;
    float o = redw[c][0][q] + redw[c][1][q] + redw[c][2][q] + redw[c][3][q] + b2v;
    out[(b * 384 + c0 + c) * 384 + q0 + q] = leaky(o);
  }
}

extern "C" void kernel_launch(void* const* d_in, const int* in_sizes, int n_in,
                              void* d_out, int out_size, void* d_ws, size_t ws_size,
                              hipStream_t stream) {
  const float* hp = (const float*)d_in[0];   // (4,384,256)
  const float* up = (const float*)d_in[1];   // (4,384,256)
  const float* w1 = (const float*)d_in[2];   // (256,768) — axis-0 is k
  const float* b1 = (const float*)d_in[3];   // (256,)
  const float* w2 = (const float*)d_in[4];   // (1,256)
  const float* b2 = (const float*)d_in[5];   // (1,)
  float* out = (float*)d_out;                // (4,384,384)

  unsigned int* wsplit = (unsigned int*)d_ws;   // fp16 [3][256][256]

  k_convert<<<384, 256, 0, stream>>>(w1, wsplit);
  k_main<<<1536, 256, 0, stream>>>(hp, up, (const _Float16*)d_ws, b1, w2, b2, out);
}